// Round 13
// baseline (68.846 us; speedup 1.0000x reference)
//
#include <hip/hip_runtime.h>

// CfdInterpolateMeshToGrid: B=8, M=8192 mesh pts/batch, G=2048 grid pts/batch,
// D=2, C=64, K=3.  out[g,c] = sum_k w_k * x[nn_k(g), c] / sum_k w_k,
// w_k = 1 / max(d2_k, 1e-16), d2 = (g2 + m2) - 2*dot.
//
// NUMERICS (locked by rounds 1-5 — DO NOT CHANGE):
//   #pragma clang fp contract(off), plus exactly:
//     m2  = (mx*mx) + (my*my)           // unfused (precomputed in bin_all,
//                                       //  same expression -> same bits)
//     g2  = (gx*gx) + (gy*gy)           // unfused
//     p0  = gx*mx; dot = fmaf(gy,my,p0) // fma-ascending k-contraction (BLAS)
//     t   = g2 + m2
//     d2  = fmaf(-2, dot, t)            // == t - (2*dot) bit-exactly
//   Selection = 3 lex-smallest (d2, idx) — identical to stable top_k and
//   visit-order independent (safe with nondeterministic bin scatter order).
//
// SCHEDULE (round 13): r12's knn_search was ~20us: wave-per-point left 56/64
// lanes idle past iter 1 and paid a 36-ds_bpermute butterfly per wave.
// Restructure: block = 256 grid points (batch-uniform);
//   - starts row staged in LDS (coalesced);
//   - THREAD-per-point serial ring scan (~72 iters x 12 insts; no shuffles);
//   - packed float4 candidates (x, y, m2, idx) -> 1 load/candidate;
//   - rare containment failures handled WAVE-cooperatively (ballot; 128-iter
//     scan + butterfly per flagged point) — never thread-serial;
//   - wave-per-point gather: 3 coalesced 256B x-rows + locked epilogue.

#define BLK 256
#define PPB 256          // grid points per search block
#define NTB 1024
#define NB 32
#define NBINS (NB * NB)
#define PADIDX 0x7FFFFFFF
#define MARGIN 1e-4f

// One block per batch: zero + histogram + exclusive scan + scatter (packed).
__global__ void bin_all(const float* __restrict__ mesh_pos,
                        int* __restrict__ starts,    // [B][NBINS+1]
                        float4* __restrict__ sxyi,   // (x, y, m2, idx_bits)
                        int M)
{
#pragma clang fp contract(off)
    __shared__ int h[NBINS];          // histogram, then cursor
    __shared__ int wsum[16];
    __shared__ int woff[17];
    const int b = blockIdx.x, t = threadIdx.x;

    h[t] = 0;                         // NBINS == NTB == 1024
    __syncthreads();

    const float2* mp = (const float2*)mesh_pos + (size_t)b * M;
    for (int n = t; n < M; n += NTB) {
        const float2 p = mp[n];
        const int bx = max(0, min((int)(p.x * (float)NB), NB - 1));
        const int by = max(0, min((int)(p.y * (float)NB), NB - 1));
        atomicAdd(&h[by * NB + bx], 1);
    }
    __syncthreads();

    const int v = h[t];
    int sc = v;                       // wave-inclusive scan
    #pragma unroll
    for (int off = 1; off < 64; off <<= 1) {
        int nv = __shfl_up(sc, off, 64);
        if ((t & 63) >= off) sc += nv;
    }
    if ((t & 63) == 63) wsum[t >> 6] = sc;
    __syncthreads();
    if (t == 0) {
        int acc = 0;
        #pragma unroll
        for (int i = 0; i < 16; ++i) { woff[i] = acc; acc += wsum[i]; }
        woff[16] = acc;
    }
    __syncthreads();
    const int excl = woff[t >> 6] + sc - v;
    starts[b * (NBINS + 1) + t] = excl;
    if (t == 0) starts[b * (NBINS + 1) + NBINS] = woff[16];   // = M
    __syncthreads();                  // everyone done reading h[t]
    h[t] = excl;                      // cursor
    __syncthreads();

    for (int n = t; n < M; n += NTB) {
        const float2 p = mp[n];       // L1 hit (just streamed)
        const int bx = max(0, min((int)(p.x * (float)NB), NB - 1));
        const int by = max(0, min((int)(p.y * (float)NB), NB - 1));
        const float m2 = (p.x * p.x) + (p.y * p.y);   // unfused (contract off)
        const int pos = atomicAdd(&h[by * NB + bx], 1);
        sxyi[(size_t)b * M + pos] =
            make_float4(p.x, p.y, m2, __int_as_float(n));  // batch-local idx
    }
}

// lex-(d2, idx) sorted-3 insert; visit-order independent == stable top_k.
#define LEX_INSERT(d2, idx)                                                  \
    if ((d2) < t2 || ((d2) == t2 && (idx) < i2)) {                           \
        if ((d2) < t1 || ((d2) == t1 && (idx) < i1)) {                       \
            t2 = t1; i2 = i1;                                                \
            if ((d2) < t0 || ((d2) == t0 && (idx) < i0)) {                   \
                t1 = t0; i1 = i0; t0 = (d2); i0 = (idx);                     \
            } else { t1 = (d2); i1 = (idx); }                                \
        } else { t2 = (d2); i2 = (idx); }                                    \
    }

// Search: block = PPB grid points. Thread-per-point selection; LDS results;
// wave-cooperative fallback; wave-per-point gather + locked epilogue.
__global__ void knn_search(const float* __restrict__ x,
                           const float* __restrict__ grid_pos,
                           const float4* __restrict__ sxyi,
                           const int* __restrict__ starts,
                           float* __restrict__ out,
                           int M, int G)
{
#pragma clang fp contract(off)
    __shared__ int   st[NBINS + 1];
    __shared__ float swd[PPB * 3];
    __shared__ int   swi[PPB * 3];

    const int tid = threadIdx.x;
    const int g0  = blockIdx.x * PPB;
    const int b   = g0 / G;               // uniform: PPB divides G

    for (int i = tid; i < NBINS + 1; i += BLK)
        st[i] = starts[b * (NBINS + 1) + i];
    __syncthreads();

    // ---- selection: one thread per grid point --------------------------
    const int g = g0 + tid;
    const float2 gp = ((const float2*)grid_pos)[g];
    const float gx = gp.x, gy = gp.y;
    const float g2 = (gx * gx) + (gy * gy);          // unfused

    const int gbx = max(0, min((int)(gx * (float)NB), NB - 1));
    const int gby = max(0, min((int)(gy * (float)NB), NB - 1));
    const int bxlo = max(gbx - 1, 0), bxhi = min(gbx + 1, NB - 1);
    const int bylo = max(gby - 1, 0), byhi = min(gby + 1, NB - 1);

    const float4* bxyi = sxyi + (size_t)b * M;

    float t0 = 1e30f, t1 = 1e30f, t2 = 1e30f;
    int   i0 = PADIDX, i1 = PADIDX, i2 = PADIDX;

    for (int ry = bylo; ry <= byhi; ++ry) {
        const int lo = st[ry * NB + bxlo];
        const int hi = st[ry * NB + bxhi + 1];
        for (int sp = lo; sp < hi; ++sp) {
            const float4 v = bxyi[sp];
            const float p0  = gx * v.x;
            const float dot = fmaf(gy, v.y, p0);
            const float t   = g2 + v.z;              // v.z = m2 (bit-exact)
            const float d2  = fmaf(-2.0f, dot, t);
            const int   idx = __float_as_int(v.w);
            LEX_INSERT(d2, idx)
        }
    }

    swd[tid * 3 + 0] = t0; swi[tid * 3 + 0] = i0;
    swd[tid * 3 + 1] = t1; swi[tid * 3 + 1] = i1;
    swd[tid * 3 + 2] = t2; swi[tid * 3 + 2] = i2;

    // Containment check: distance to unexamined region.
    const float w = 1.0f / (float)NB;
    const float dl = (bxlo > 0)      ? (gx - (float)bxlo * w)       : 1e30f;
    const float dr = (bxhi < NB - 1) ? ((float)(bxhi + 1) * w - gx) : 1e30f;
    const float dn = (bylo > 0)      ? (gy - (float)bylo * w)       : 1e30f;
    const float dt = (byhi < NB - 1) ? ((float)(byhi + 1) * w - gy) : 1e30f;
    const float bdd = fminf(fminf(dl, dr), fminf(dn, dt));
    const float bd2 = bdd * bdd;
    const bool need = !(t2 + MARGIN < bd2);

    // ---- rare fallback: wave-cooperative exact full-batch scan ---------
    const int lane = tid & 63;
    unsigned long long mask = __ballot(need);
    while (mask) {
        const int l = __builtin_ctzll(mask); mask &= mask - 1;
        const int pt = (tid & ~63) + l;              // block-local point
        const float2 fgp = ((const float2*)grid_pos)[g0 + pt];
        const float fgx = fgp.x, fgy = fgp.y;
        const float fg2 = (fgx * fgx) + (fgy * fgy); // unfused
        float t0 = 1e30f, t1 = 1e30f, t2 = 1e30f;
        int   i0 = PADIDX, i1 = PADIDX, i2 = PADIDX;
        for (int j = lane; j < M; j += 64) {
            const float4 v = bxyi[j];
            const float p0  = fgx * v.x;
            const float dot = fmaf(fgy, v.y, p0);
            const float t   = fg2 + v.z;
            const float d2  = fmaf(-2.0f, dot, t);
            const int   idx = __float_as_int(v.w);
            LEX_INSERT(d2, idx)
        }
        #pragma unroll
        for (int r = 0; r < 3; ++r) {                // butterfly extract
            float rd = t0; int ri = i0;
            #pragma unroll
            for (int off = 32; off; off >>= 1) {
                float od = __shfl_xor(rd, off, 64);
                int   oi = __shfl_xor(ri, off, 64);
                if (od < rd || (od == rd && oi < ri)) { rd = od; ri = oi; }
            }
            if (lane == 0) { swd[pt * 3 + r] = rd; swi[pt * 3 + r] = ri; }
            if (t0 == rd && i0 == ri) {
                t0 = t1; i0 = i1; t1 = t2; i1 = i2; t2 = 1e30f; i2 = PADIDX;
            }
        }
    }
    __syncthreads();

    // ---- gather: wave per point, lane = channel ------------------------
    const int wv = tid >> 6;
    const size_t rowBase = (size_t)b * M * 64;
    #pragma unroll 2
    for (int q = 0; q < 64; ++q) {
        const int pt = (wv << 6) + q;
        const float w0 = 1.0f / fmaxf(swd[pt * 3 + 0], 1e-16f);
        const float w1 = 1.0f / fmaxf(swd[pt * 3 + 1], 1e-16f);
        const float w2 = 1.0f / fmaxf(swd[pt * 3 + 2], 1e-16f);
        const int   j0 = swi[pt * 3 + 0];
        const int   j1 = swi[pt * 3 + 1];
        const int   j2 = swi[pt * 3 + 2];
        const float x0 = x[rowBase + (size_t)j0 * 64 + lane];
        const float x1 = x[rowBase + (size_t)j1 * 64 + lane];
        const float x2 = x[rowBase + (size_t)j2 * 64 + lane];
        const float num = ((w0 * x0) + (w1 * x1)) + (w2 * x2);  // unfused
        const float den = (w0 + w1) + w2;
        out[(size_t)(g0 + pt) * 64 + lane] = num / den;
    }
}

extern "C" void kernel_launch(void* const* d_in, const int* in_sizes, int n_in,
                              void* d_out, int out_size, void* d_ws, size_t ws_size,
                              hipStream_t stream) {
    const float* x        = (const float*)d_in[0];
    const float* mesh_pos = (const float*)d_in[1];
    const float* grid_pos = (const float*)d_in[2];
    // d_in[3] = batch_idx (int64) — contiguous repeat layout, unused.

    const int N  = in_sizes[1] / 2;   // 65536
    const int Gt = in_sizes[2] / 2;   // 16384
    const int B  = 8;
    const int M  = N / B;             // 8192
    const int G  = Gt / B;            // 2048

    // Workspace (~1.1 MB): starts + packed candidates.
    char* p = (char*)d_ws;
    int*    starts = (int*)p;     p += (size_t)B * (NBINS + 1) * sizeof(int);
    float4* sxyi   = (float4*)p;

    bin_all   <<<B, NTB, 0, stream>>>(mesh_pos, starts, sxyi, M);
    knn_search<<<Gt / PPB, BLK, 0, stream>>>(x, grid_pos, sxyi, starts,
                                             (float*)d_out, M, G);
}

// Round 14
// 27.814 us; speedup vs baseline: 2.4752x; 2.4752x over previous
//
#include <hip/hip_runtime.h>

// CfdInterpolateMeshToGrid: B=8, M=8192 mesh pts/batch, G=2048 grid pts/batch,
// D=2, C=64, K=3.  out[g,c] = sum_k w_k * x[nn_k(g), c] / sum_k w_k,
// w_k = 1 / max(d2_k, 1e-16), d2 = (g2 + m2) - 2*dot.
//
// NUMERICS (locked by rounds 1-5 — DO NOT CHANGE):
//   #pragma clang fp contract(off), plus exactly:
//     m2  = (mx*mx) + (my*my)           // unfused (precomputed in bin_all)
//     g2  = (gx*gx) + (gy*gy)           // unfused
//     p0  = gx*mx; dot = fmaf(gy,my,p0) // fma-ascending k-contraction (BLAS)
//     t   = g2 + m2
//     d2  = fmaf(-2, dot, t)            // == t - (2*dot) bit-exactly
//   Selection = 3 lex-smallest (d2, idx) — identical to stable top_k and
//   visit-order independent (safe with nondeterministic bin scatter order).
//
// SCHEDULE (round 14): r13's thread-per-point shrank the grid to 64 blocks
// (occupancy 2.3%, VALUBusy 4.6% -> 58us of bare latency). Fix granularity:
// 8 LANES PER POINT. Block = 256 thr = 32 points -> 512 blocks (8 waves/CU,
// the r6/r10-proven regime). Ring candidates strided across the 8 lanes
// (consecutive float4 -> coalesced 128B/group, ~9 independent loads/lane);
// merge = 3 rounds x 3-level shfl_xor lex extract-pop (18 shuffles/wave for
// 8 points vs r12's 36/point). starts read from L2 (4KB/batch, cached) —
// no LDS staging; SoA result arrays (no bank conflicts). Fallback (rare)
// wave-cooperative; gather wave-per-point, lane=channel.

#define BLK 256
#define PPB 32           // grid points per search block (256 thr / 8 lanes)
#define NTB 1024
#define NB 32
#define NBINS (NB * NB)
#define PADIDX 0x7FFFFFFF
#define MARGIN 1e-4f

// One block per batch: zero + histogram + exclusive scan + scatter (packed).
__global__ void bin_all(const float* __restrict__ mesh_pos,
                        int* __restrict__ starts,    // [B][NBINS+1]
                        float4* __restrict__ sxyi,   // (x, y, m2, idx_bits)
                        int M)
{
#pragma clang fp contract(off)
    __shared__ int h[NBINS];          // histogram, then cursor
    __shared__ int wsum[16];
    __shared__ int woff[17];
    const int b = blockIdx.x, t = threadIdx.x;

    h[t] = 0;                         // NBINS == NTB == 1024
    __syncthreads();

    const float2* mp = (const float2*)mesh_pos + (size_t)b * M;
    for (int n = t; n < M; n += NTB) {
        const float2 p = mp[n];
        const int bx = max(0, min((int)(p.x * (float)NB), NB - 1));
        const int by = max(0, min((int)(p.y * (float)NB), NB - 1));
        atomicAdd(&h[by * NB + bx], 1);
    }
    __syncthreads();

    const int v = h[t];
    int sc = v;                       // wave-inclusive scan
    #pragma unroll
    for (int off = 1; off < 64; off <<= 1) {
        int nv = __shfl_up(sc, off, 64);
        if ((t & 63) >= off) sc += nv;
    }
    if ((t & 63) == 63) wsum[t >> 6] = sc;
    __syncthreads();
    if (t == 0) {
        int acc = 0;
        #pragma unroll
        for (int i = 0; i < 16; ++i) { woff[i] = acc; acc += wsum[i]; }
        woff[16] = acc;
    }
    __syncthreads();
    const int excl = woff[t >> 6] + sc - v;
    starts[b * (NBINS + 1) + t] = excl;
    if (t == 0) starts[b * (NBINS + 1) + NBINS] = woff[16];   // = M
    __syncthreads();                  // everyone done reading h[t]
    h[t] = excl;                      // cursor
    __syncthreads();

    for (int n = t; n < M; n += NTB) {
        const float2 p = mp[n];       // L1 hit (just streamed)
        const int bx = max(0, min((int)(p.x * (float)NB), NB - 1));
        const int by = max(0, min((int)(p.y * (float)NB), NB - 1));
        const float m2 = (p.x * p.x) + (p.y * p.y);   // unfused (contract off)
        const int pos = atomicAdd(&h[by * NB + bx], 1);
        sxyi[(size_t)b * M + pos] =
            make_float4(p.x, p.y, m2, __int_as_float(n));  // batch-local idx
    }
}

// lex-(d2, idx) sorted-3 insert; visit-order independent == stable top_k.
#define LEX_INSERT(d2, idx)                                                  \
    if ((d2) < t2 || ((d2) == t2 && (idx) < i2)) {                           \
        if ((d2) < t1 || ((d2) == t1 && (idx) < i1)) {                       \
            t2 = t1; i2 = i1;                                                \
            if ((d2) < t0 || ((d2) == t0 && (idx) < i0)) {                   \
                t1 = t0; i1 = i0; t0 = (d2); i0 = (idx);                     \
            } else { t1 = (d2); i1 = (idx); }                                \
        } else { t2 = (d2); i2 = (idx); }                                    \
    }

// Search: block = 32 grid points, 8 lanes each.
__global__ void knn_search(const float* __restrict__ x,
                           const float* __restrict__ grid_pos,
                           const float4* __restrict__ sxyi,
                           const int* __restrict__ starts,
                           float* __restrict__ out,
                           int M, int G)
{
#pragma clang fp contract(off)
    __shared__ float swd0[PPB], swd1[PPB], swd2[PPB];
    __shared__ int   swi0[PPB], swi1[PPB], swi2[PPB];

    const int tid  = threadIdx.x;
    const int g0   = blockIdx.x * PPB;
    const int b    = g0 / G;              // uniform: PPB divides G
    const int pt   = tid >> 3;            // block-local point 0..31
    const int li   = tid & 7;             // lane within point group
    const int lane = tid & 63;

    const int g = g0 + pt;
    const float2 gp = ((const float2*)grid_pos)[g];   // broadcast in group
    const float gx = gp.x, gy = gp.y;
    const float g2 = (gx * gx) + (gy * gy);           // unfused

    const int gbx = max(0, min((int)(gx * (float)NB), NB - 1));
    const int gby = max(0, min((int)(gy * (float)NB), NB - 1));
    const int bxlo = max(gbx - 1, 0), bxhi = min(gbx + 1, NB - 1);
    const int bylo = max(gby - 1, 0), byhi = min(gby + 1, NB - 1);

    const int* st = starts + b * (NBINS + 1);          // L2-resident (4KB)
    const float4* bxyi = sxyi + (size_t)b * M;

    float t0 = 1e30f, t1 = 1e30f, t2 = 1e30f;
    int   i0 = PADIDX, i1 = PADIDX, i2 = PADIDX;

    for (int ry = bylo; ry <= byhi; ++ry) {
        const int lo = st[ry * NB + bxlo];
        const int hi = st[ry * NB + bxhi + 1];
        for (int sp = lo + li; sp < hi; sp += 8) {     // coalesced 128B/group
            const float4 v = bxyi[sp];
            const float p0  = gx * v.x;
            const float dot = fmaf(gy, v.y, p0);
            const float t   = g2 + v.z;                // v.z = m2 (bit-exact)
            const float d2  = fmaf(-2.0f, dot, t);
            const int   idx = __float_as_int(v.w);
            LEX_INSERT(d2, idx)
        }
    }

    // 8-lane lex extract-pop x3. Global-top-3 of the group is contained in
    // the union of per-lane sorted-3s; idx uniqueness -> exactly one pop.
    float wd2last = 1e30f;
    #pragma unroll
    for (int r = 0; r < 3; ++r) {
        float rd = t0; int ri = i0;
        #pragma unroll
        for (int off = 1; off < 8; off <<= 1) {
            float od = __shfl_xor(rd, off, 64);
            int   oi = __shfl_xor(ri, off, 64);
            if (od < rd || (od == rd && oi < ri)) { rd = od; ri = oi; }
        }
        if (li == 0) {
            if (r == 0)      { swd0[pt] = rd; swi0[pt] = ri; }
            else if (r == 1) { swd1[pt] = rd; swi1[pt] = ri; }
            else             { swd2[pt] = rd; swi2[pt] = ri; }
        }
        wd2last = rd;
        if (t0 == rd && i0 == ri) {
            t0 = t1; i0 = i1; t1 = t2; i1 = i2; t2 = 1e30f; i2 = PADIDX;
        }
    }

    // Containment check (group-uniform): distance to unexamined region.
    const float w = 1.0f / (float)NB;
    const float dl = (bxlo > 0)      ? (gx - (float)bxlo * w)       : 1e30f;
    const float dr = (bxhi < NB - 1) ? ((float)(bxhi + 1) * w - gx) : 1e30f;
    const float dn = (bylo > 0)      ? (gy - (float)bylo * w)       : 1e30f;
    const float dt = (byhi < NB - 1) ? ((float)(byhi + 1) * w - gy) : 1e30f;
    const float bdd = fminf(fminf(dl, dr), fminf(dn, dt));
    const float bd2 = bdd * bdd;
    const bool need = (li == 0) && !(wd2last + MARGIN < bd2);

    // ---- rare fallback: wave-cooperative exact full-batch scan ---------
    unsigned long long mask = __ballot(need);
    while (mask) {
        const int l = __builtin_ctzll(mask); mask &= mask - 1;
        const int ptf = ((tid & ~63) + l) >> 3;        // block-local point
        const float2 fgp = ((const float2*)grid_pos)[g0 + ptf];
        const float fgx = fgp.x, fgy = fgp.y;
        const float fg2 = (fgx * fgx) + (fgy * fgy);   // unfused
        float t0 = 1e30f, t1 = 1e30f, t2 = 1e30f;
        int   i0 = PADIDX, i1 = PADIDX, i2 = PADIDX;
        for (int j = lane; j < M; j += 64) {
            const float4 v = bxyi[j];
            const float p0  = fgx * v.x;
            const float dot = fmaf(fgy, v.y, p0);
            const float t   = fg2 + v.z;
            const float d2  = fmaf(-2.0f, dot, t);
            const int   idx = __float_as_int(v.w);
            LEX_INSERT(d2, idx)
        }
        #pragma unroll
        for (int r = 0; r < 3; ++r) {                  // 64-lane butterfly
            float rd = t0; int ri = i0;
            #pragma unroll
            for (int off = 32; off; off >>= 1) {
                float od = __shfl_xor(rd, off, 64);
                int   oi = __shfl_xor(ri, off, 64);
                if (od < rd || (od == rd && oi < ri)) { rd = od; ri = oi; }
            }
            if (lane == 0) {
                if (r == 0)      { swd0[ptf] = rd; swi0[ptf] = ri; }
                else if (r == 1) { swd1[ptf] = rd; swi1[ptf] = ri; }
                else             { swd2[ptf] = rd; swi2[ptf] = ri; }
            }
            if (t0 == rd && i0 == ri) {
                t0 = t1; i0 = i1; t1 = t2; i1 = i2; t2 = 1e30f; i2 = PADIDX;
            }
        }
    }
    __syncthreads();

    // ---- gather: wave per point (8 each), lane = channel ----------------
    const int wv = tid >> 6;
    const size_t rowBase = (size_t)b * M * 64;
    #pragma unroll 2
    for (int q = 0; q < 8; ++q) {
        const int ptq = (wv << 3) + q;
        const float w0 = 1.0f / fmaxf(swd0[ptq], 1e-16f);
        const float w1 = 1.0f / fmaxf(swd1[ptq], 1e-16f);
        const float w2 = 1.0f / fmaxf(swd2[ptq], 1e-16f);
        const int   j0 = swi0[ptq];
        const int   j1 = swi1[ptq];
        const int   j2 = swi2[ptq];
        const float x0 = x[rowBase + (size_t)j0 * 64 + lane];
        const float x1 = x[rowBase + (size_t)j1 * 64 + lane];
        const float x2 = x[rowBase + (size_t)j2 * 64 + lane];
        const float num = ((w0 * x0) + (w1 * x1)) + (w2 * x2);  // unfused
        const float den = (w0 + w1) + w2;
        out[(size_t)(g0 + ptq) * 64 + lane] = num / den;
    }
}

extern "C" void kernel_launch(void* const* d_in, const int* in_sizes, int n_in,
                              void* d_out, int out_size, void* d_ws, size_t ws_size,
                              hipStream_t stream) {
    const float* x        = (const float*)d_in[0];
    const float* mesh_pos = (const float*)d_in[1];
    const float* grid_pos = (const float*)d_in[2];
    // d_in[3] = batch_idx (int64) — contiguous repeat layout, unused.

    const int N  = in_sizes[1] / 2;   // 65536
    const int Gt = in_sizes[2] / 2;   // 16384
    const int B  = 8;
    const int M  = N / B;             // 8192
    const int G  = Gt / B;            // 2048

    // Workspace (~1.1 MB): starts + packed candidates.
    char* p = (char*)d_ws;
    int*    starts = (int*)p;     p += (size_t)B * (NBINS + 1) * sizeof(int);
    float4* sxyi   = (float4*)p;

    bin_all   <<<B, NTB, 0, stream>>>(mesh_pos, starts, sxyi, M);
    knn_search<<<Gt / PPB, BLK, 0, stream>>>(x, grid_pos, sxyi, starts,
                                             (float*)d_out, M, G);
}